// Round 3
// baseline (174.802 us; speedup 1.0000x reference)
//
#include <hip/hip_runtime.h>

#define N_PTS 2048
#define BATCH 64
#define P 2            // query points per thread
#define BLK 256        // threads per block
#define QPB (P * BLK)  // 512 queries per block
#define NRM_Q 0                  // ws float offset of |q|^2 table
#define NRM_P (BATCH * N_PTS)    // ws float offset of |p|^2 table
#define NRM_FLOATS (2 * BATCH * N_PTS)

// prepass: per-point squared norms for both sides into d_ws.
// grid: 128 blocks (side*64 + batch), 256 threads.
__global__ __launch_bounds__(BLK) void norms_kernel(
        const float4* __restrict__ p,
        const float4* __restrict__ q,
        float* __restrict__ nrm) {
    const int side = blockIdx.x >> 6;   // 0 = q norms, 1 = p norms
    const int b    = blockIdx.x & 63;
    const float4* __restrict__ src = (side ? p : q) + (size_t)b * N_PTS;
    float* __restrict__ dst = nrm + (side ? NRM_P : NRM_Q) + (size_t)b * N_PTS;
    for (int i = threadIdx.x; i < N_PTS; i += BLK) {
        const float4 v = src[i];
        dst[i] = v.x * v.x + v.y * v.y + v.z * v.z + v.w * v.w;
    }
}

// grid: (N_PTS/QPB=4, BATCH, 2 dirs), block: 256.
// Search side read with WAVE-UNIFORM indices directly from global -> compiler
// scalarizes to s_load; inner math: t = |q_j|^2 + (-2p)·q_j via 4 v_fma
// (1 SGPR operand each), two j's folded into one v_min3_f32.
template <bool USE_NRM>
__global__ __launch_bounds__(BLK) void chamfer_kernel(
        const float4* __restrict__ p,
        const float4* __restrict__ q,
        const float* __restrict__ nrm,
        float* __restrict__ out) {
    __shared__ float  wsum[4];
    __shared__ float4 wacc[4];

    const int tid = threadIdx.x;
    const int b   = blockIdx.y;
    const int dir = blockIdx.z;
    const float4* __restrict__ Ab = (dir ? q : p) + (size_t)b * N_PTS;  // queries
    const float4* __restrict__ Bb = (dir ? p : q) + (size_t)b * N_PTS;  // search
    const float4* __restrict__ Bs =
        (const float4*)(nrm + (dir ? NRM_P : NRM_Q)) + (size_t)b * (N_PTS / 4);

    const int base = blockIdx.x * QPB;

    float4 pm[P];
    float  mn[P];
    float  psq = 0.0f;
#pragma unroll
    for (int k = 0; k < P; ++k) {
        const float4 pv = Ab[base + tid + k * BLK];
        psq += pv.x * pv.x + pv.y * pv.y + pv.z * pv.z + pv.w * pv.w;
        pm[k] = make_float4(-2.0f * pv.x, -2.0f * pv.y, -2.0f * pv.z, -2.0f * pv.w);
        mn[k] = 3.4e38f;
    }

#define DIST(T, QV, QS)                       \
    float T = fmaf(pm[k].x, (QV).x, (QS));    \
    T = fmaf(pm[k].y, (QV).y, T);             \
    T = fmaf(pm[k].z, (QV).z, T);             \
    T = fmaf(pm[k].w, (QV).w, T);

#pragma unroll 2
    for (int g = 0; g < N_PTS / 4; ++g) {
        const float4 q0 = Bb[4 * g + 0];   // uniform -> s_load
        const float4 q1 = Bb[4 * g + 1];
        const float4 q2 = Bb[4 * g + 2];
        const float4 q3 = Bb[4 * g + 3];
        float4 qs;
        if (USE_NRM) {
            qs = Bs[g];                    // uniform -> s_load
        } else {
            qs.x = q0.x * q0.x + q0.y * q0.y + q0.z * q0.z + q0.w * q0.w;
            qs.y = q1.x * q1.x + q1.y * q1.y + q1.z * q1.z + q1.w * q1.w;
            qs.z = q2.x * q2.x + q2.y * q2.y + q2.z * q2.z + q2.w * q2.w;
            qs.w = q3.x * q3.x + q3.y * q3.y + q3.z * q3.z + q3.w * q3.w;
        }
#pragma unroll
        for (int k = 0; k < P; ++k) {
            DIST(t0, q0, qs.x)
            DIST(t1, q1, qs.y)
            mn[k] = fminf(fminf(mn[k], t0), t1);   // -> v_min3_f32
            DIST(t2, q2, qs.z)
            DIST(t3, q3, qs.w)
            mn[k] = fminf(fminf(mn[k], t2), t3);
        }
    }
#undef DIST

    float s = psq;
#pragma unroll
    for (int k = 0; k < P; ++k) s += mn[k];

#pragma unroll
    for (int off = 32; off > 0; off >>= 1) s += __shfl_down(s, off, 64);
    const int lane = tid & 63;
    const int wid  = tid >> 6;
    if (lane == 0) wsum[wid] = s;
    __syncthreads();
    if (tid == 0) atomicAdd(out, wsum[0] + wsum[1] + wsum[2] + wsum[3]);

    // fused jet term: 64 blocks (dir==0, x==0), one per batch
    if (dir == 0 && blockIdx.x == 0) {
        float ax = 0.f, ay = 0.f, az = 0.f, aw = 0.f;
        for (int j = tid; j < N_PTS; j += BLK) {
            const float4 pv = Ab[j];
            const float4 qv = Bb[j];
            ax += pv.x - qv.x;
            ay += pv.y - qv.y;
            az += pv.z - qv.z;
            aw += pv.w - qv.w;
        }
#pragma unroll
        for (int off = 32; off > 0; off >>= 1) {
            ax += __shfl_down(ax, off, 64);
            ay += __shfl_down(ay, off, 64);
            az += __shfl_down(az, off, 64);
            aw += __shfl_down(aw, off, 64);
        }
        if (lane == 0) wacc[wid] = make_float4(ax, ay, az, aw);
        __syncthreads();
        if (tid == 0) {
            float dx = 0.f, dy = 0.f, dz = 0.f, dw = 0.f;
#pragma unroll
            for (int w = 0; w < 4; ++w) {
                dx += wacc[w].x;
                dy += wacc[w].y;
                dz += wacc[w].z;
                dw += wacc[w].w;
            }
            atomicAdd(out, dx * dx + dy * dy + dz * dz + dw * dw);
        }
    }
}

extern "C" void kernel_launch(void* const* d_in, const int* in_sizes, int n_in,
                              void* d_out, int out_size, void* d_ws, size_t ws_size,
                              hipStream_t stream) {
    const float4* p = (const float4*)d_in[0];
    const float4* q = (const float4*)d_in[1];
    float* out = (float*)d_out;
    float* nrm = (float*)d_ws;

    hipMemsetAsync(out, 0, sizeof(float), stream);
    const dim3 grid(N_PTS / QPB, BATCH, 2);
    if (ws_size >= NRM_FLOATS * sizeof(float)) {
        norms_kernel<<<128, BLK, 0, stream>>>(p, q, nrm);
        chamfer_kernel<true><<<grid, BLK, 0, stream>>>(p, q, nrm, out);
    } else {
        chamfer_kernel<false><<<grid, BLK, 0, stream>>>(p, q, nrm, out);
    }
}

// Round 4
// 165.497 us; speedup vs baseline: 1.0562x; 1.0562x over previous
//
#include <hip/hip_runtime.h>

#define N_PTS 2048
#define BATCH 64
#define BLK 64                 // one wave per block
#define P 4                    // query points per thread
#define QPB (P * BLK)          // 256 queries per block
#define TILES (N_PTS / 64)     // 32 tiles of 64 search points

__device__ __forceinline__ float rl(float v, int l) {
    return __uint_as_float((unsigned)__builtin_amdgcn_readlane((int)__float_as_uint(v), l));
}

// grid: (N_PTS/QPB=8, BATCH, 2 dirs), block: 64 (one wave).
// Search points stream through per-lane coalesced VMEM loads (64 pts/tile),
// then broadcast to SGPRs via v_readlane (VALU pipe, imm lane). Inner math:
// t = |q|^2 + (-2p)·q = 4 v_fma (1 SGPR operand each); two points fold into
// one v_min3_f32 per query. No LDS, no s_load in the hot loop.
__global__ __launch_bounds__(BLK) void chamfer_kernel(
        const float4* __restrict__ p,
        const float4* __restrict__ q,
        float* __restrict__ out) {
    const int lane = threadIdx.x;          // 0..63
    const int b    = blockIdx.y;
    const int dir  = blockIdx.z;
    const float4* __restrict__ Ab = (dir ? q : p) + (size_t)b * N_PTS;  // queries
    const float4* __restrict__ Bb = (dir ? p : q) + (size_t)b * N_PTS;  // search

    const int base = blockIdx.x * QPB;

    float4 pm[P];   // -2 * query point
    float  mn[P];
    float  psq = 0.0f;
#pragma unroll
    for (int k = 0; k < P; ++k) {
        const float4 pv = Ab[base + lane + k * BLK];
        psq += pv.x * pv.x + pv.y * pv.y + pv.z * pv.z + pv.w * pv.w;
        pm[k] = make_float4(-2.0f * pv.x, -2.0f * pv.y, -2.0f * pv.z, -2.0f * pv.w);
        mn[k] = 3.4e38f;
    }

    float4 v = Bb[lane];                   // tile 0, one point per lane
#pragma unroll 1
    for (int t = 0; t < TILES; ++t) {
        // prefetch next tile (tile 0 again on the last iter — harmless)
        const float4 vn = Bb[(((t + 1) & (TILES - 1)) << 6) + lane];
        const float qs = v.x * v.x + v.y * v.y + v.z * v.z + v.w * v.w;

#pragma unroll
        for (int l = 0; l < 64; l += 2) {
            const float q0x = rl(v.x, l),     q0y = rl(v.y, l);
            const float q0z = rl(v.z, l),     q0w = rl(v.w, l);
            const float q0s = rl(qs,  l);
            const float q1x = rl(v.x, l + 1), q1y = rl(v.y, l + 1);
            const float q1z = rl(v.z, l + 1), q1w = rl(v.w, l + 1);
            const float q1s = rl(qs,  l + 1);
#pragma unroll
            for (int k = 0; k < P; ++k) {
                float t0 = fmaf(pm[k].x, q0x, q0s);
                t0 = fmaf(pm[k].y, q0y, t0);
                t0 = fmaf(pm[k].z, q0z, t0);
                t0 = fmaf(pm[k].w, q0w, t0);
                float t1 = fmaf(pm[k].x, q1x, q1s);
                t1 = fmaf(pm[k].y, q1y, t1);
                t1 = fmaf(pm[k].z, q1z, t1);
                t1 = fmaf(pm[k].w, q1w, t1);
                mn[k] = fminf(fminf(mn[k], t0), t1);   // -> v_min3_f32
            }
        }
        v = vn;
    }

    float s = psq;
#pragma unroll
    for (int k = 0; k < P; ++k) s += mn[k];

#pragma unroll
    for (int off = 32; off > 0; off >>= 1) s += __shfl_down(s, off, 64);
    if (lane == 0) atomicAdd(out, s);

    // fused jet term: blocks (dir==0, x==0), one per batch; Ab=p_b, Bb=q_b
    if (dir == 0 && blockIdx.x == 0) {
        float ax = 0.f, ay = 0.f, az = 0.f, aw = 0.f;
        for (int j = lane; j < N_PTS; j += BLK) {
            const float4 pv = Ab[j];
            const float4 qv = Bb[j];
            ax += pv.x - qv.x;
            ay += pv.y - qv.y;
            az += pv.z - qv.z;
            aw += pv.w - qv.w;
        }
#pragma unroll
        for (int off = 32; off > 0; off >>= 1) {
            ax += __shfl_down(ax, off, 64);
            ay += __shfl_down(ay, off, 64);
            az += __shfl_down(az, off, 64);
            aw += __shfl_down(aw, off, 64);
        }
        if (lane == 0) atomicAdd(out, ax * ax + ay * ay + az * az + aw * aw);
    }
}

extern "C" void kernel_launch(void* const* d_in, const int* in_sizes, int n_in,
                              void* d_out, int out_size, void* d_ws, size_t ws_size,
                              hipStream_t stream) {
    const float4* p = (const float4*)d_in[0];
    const float4* q = (const float4*)d_in[1];
    float* out = (float*)d_out;

    hipMemsetAsync(out, 0, sizeof(float), stream);
    chamfer_kernel<<<dim3(N_PTS / QPB, BATCH, 2), BLK, 0, stream>>>(p, q, out);
}